// Round 1
// baseline (1493.911 us; speedup 1.0000x reference)
//
#include <hip/hip_runtime.h>
#include <hip/hip_bf16.h>
#include <math.h>

#define N_NODES 50000
#define N_EDGES 800000
#define CH 128

// ---------------------------------------------------------------------------
// Kernel 1: xt = x @ W^T + b
// Block: 256 threads = 8 rows x 32 col-groups (4 cols each, float4).
// W^T staged in LDS, k-major, with 16B-group XOR swizzle so that BOTH the
// transpose-write (k varies across lanes) and the compute-read (cg varies
// across lanes) are bank-conflict-free.
//   element (c,k) stored at: wt[(k<<7) + (((c>>2) ^ (k&31))<<2) + (c&3)]
// ---------------------------------------------------------------------------
__global__ __launch_bounds__(256) void gemm_xt(const float* __restrict__ x,
                                               const float* __restrict__ W,
                                               const float* __restrict__ bias_p,
                                               float* __restrict__ xt,
                                               int rows_per_block) {
    __shared__ float wt[128 * 128];   // 64 KB
    __shared__ float xs[8][128];      // 4 KB

    const int tid = threadIdx.x;
    const int cg  = tid & 31;   // col group (4 cols)
    const int r   = tid >> 5;   // row within 8-row tile

    // Stage W transposed + swizzled. Global read coalesced (i consecutive ->
    // consecutive k of one W row); LDS write banks = ((cg^k)&31)*4 + (c&3),
    // k distinct across lanes -> conflict-free.
    for (int i = tid; i < 128 * 128; i += 256) {
        int c = i >> 7, k = i & 127;
        wt[(k << 7) + ((((c >> 2) ^ (k & 31))) << 2) + (c & 3)] = W[i];
    }
    const float4 bias = reinterpret_cast<const float4*>(bias_p)[cg];
    __syncthreads();

    const int row0    = blockIdx.x * rows_per_block;
    const int row_end = min(row0 + rows_per_block, N_NODES);

    for (int rb = row0; rb < row_end; rb += 8) {
        const int nrows = min(8, N_NODES - rb);
        {   // load up to 8 rows of x: 256 float4, coalesced
            const int rr = tid >> 5;
            const int kk = tid & 31;
            if (rr < nrows)
                reinterpret_cast<float4*>(&xs[rr][0])[kk] =
                    reinterpret_cast<const float4*>(&x[(size_t)(rb + rr) * CH])[kk];
        }
        __syncthreads();

        float4 acc = {0.f, 0.f, 0.f, 0.f};
        #pragma unroll
        for (int k = 0; k < 128; ++k) {
            const float xv = xs[r][k];                       // broadcast read
            const float4 wv = *reinterpret_cast<const float4*>(
                &wt[(k << 7) + ((cg ^ (k & 31)) << 2)]);     // b128, no conflict
            acc.x += xv * wv.x;
            acc.y += xv * wv.y;
            acc.z += xv * wv.z;
            acc.w += xv * wv.w;
        }

        if (r < nrows) {
            acc.x += bias.x; acc.y += bias.y; acc.z += bias.z; acc.w += bias.w;
            reinterpret_cast<float4*>(&xt[(size_t)(rb + r) * CH])[cg] = acc;
        }
        __syncthreads();
    }
}

// ---------------------------------------------------------------------------
// Kernel 2: out[row] += xt[col]  (atomic scatter-add)
// One thread per (edge, 4 channels): float4 gather + 4 scalar atomicAdds.
// ---------------------------------------------------------------------------
__global__ __launch_bounds__(256) void scatter_add(const int* __restrict__ ei,
                                                   const float* __restrict__ xt,
                                                   float* __restrict__ out) {
    const int gid = blockIdx.x * 256 + threadIdx.x;
    const int e = gid >> 5;
    if (e >= N_EDGES) return;
    const int lane = gid & 31;
    const int row = ei[e];
    const int col = ei[N_EDGES + e];
    const float4 v = reinterpret_cast<const float4*>(&xt[(size_t)col * CH])[lane];
    float* dst = &out[(size_t)row * CH + lane * 4];
    atomicAdd(dst + 0, v.x);
    atomicAdd(dst + 1, v.y);
    atomicAdd(dst + 2, v.z);
    atomicAdd(dst + 3, v.w);
}

// ---------------------------------------------------------------------------
// Kernel 3: out = tanh(out), in place, float4
// ---------------------------------------------------------------------------
__global__ __launch_bounds__(256) void tanh_inplace(float* __restrict__ out) {
    const int i = blockIdx.x * 256 + threadIdx.x;
    if (i < N_NODES * CH / 4) {
        float4* p = reinterpret_cast<float4*>(out);
        float4 v = p[i];
        v.x = tanhf(v.x);
        v.y = tanhf(v.y);
        v.z = tanhf(v.z);
        v.w = tanhf(v.w);
        p[i] = v;
    }
}

extern "C" void kernel_launch(void* const* d_in, const int* in_sizes, int n_in,
                              void* d_out, int out_size, void* d_ws, size_t ws_size,
                              hipStream_t stream) {
    const float* x  = (const float*)d_in[0];
    const int*   ei = (const int*)d_in[1];
    const float* W  = (const float*)d_in[2];
    const float* b  = (const float*)d_in[3];
    float* out = (float*)d_out;
    float* xt  = (float*)d_ws;   // 50000*128*4 = 25.6 MB scratch

    // zero the accumulator (harness poisons d_out with 0xAA)
    hipMemsetAsync(d_out, 0, (size_t)N_NODES * CH * sizeof(float), stream);

    const int rpb = 104;                              // rows per block (mult of 8)
    const int gblocks = (N_NODES + rpb - 1) / rpb;    // 481
    gemm_xt<<<gblocks, 256, 0, stream>>>(x, W, b, xt, rpb);

    const int sblocks = (N_EDGES * 32 + 255) / 256;   // 100000
    scatter_add<<<sblocks, 256, 0, stream>>>(ei, xt, out);

    const int tblocks = (N_NODES * CH / 4 + 255) / 256;
    tanh_inplace<<<tblocks, 256, 0, stream>>>(out);
}

// Round 5
// 323.284 us; speedup vs baseline: 4.6210x; 4.6210x over previous
//
#include <hip/hip_runtime.h>
#include <hip/hip_bf16.h>
#include <hip/hip_fp16.h>
#include <math.h>

#define N_NODES 50000
#define N_EDGES 800000
#define CH 128

// ---------------------------------------------------------------------------
// Kernel 1: xt (fp16) = x @ W^T + b
// 256 threads = 32 col-groups (4 cols) x 8 row-groups (4 rows) -> 32r x 128c
// per tile. Both W^T and the x-tile live in LDS transposed ([k][...]) with
// XOR swizzle; per k each thread does 2 b128 reads feeding 16 fp32 FMAs
// (VALU-bound). Output stored fp16 to halve gather traffic downstream.
//   wt word: (k<<7) + (((c>>2) ^ (k&31))<<2) + (c&3)       (proven 0-conflict)
//   xs word: (k<<5) + (((r>>2) ^ ((k>>2)&7))<<2) + (r&3)
// ---------------------------------------------------------------------------
__global__ __launch_bounds__(256) void gemm_xt_f16(const float* __restrict__ x,
                                                   const float* __restrict__ W,
                                                   const float* __restrict__ bias_p,
                                                   __half* __restrict__ xt,
                                                   int rows_per_block) {
    __shared__ float wt[128 * 128];   // 64 KB
    __shared__ float xs[128 * 32];    // 16 KB (32-row x-tile, transposed)

    const int tid = threadIdx.x;
    const int cg  = tid & 31;   // col group (4 cols)
    const int rg  = tid >> 5;   // row group (4 rows), 0..7

    for (int i = tid; i < 128 * 128; i += 256) {
        int c = i >> 7, k = i & 127;
        wt[(k << 7) + ((((c >> 2) ^ (k & 31))) << 2) + (c & 3)] = W[i];
    }
    const float4 bias = reinterpret_cast<const float4*>(bias_p)[cg];
    __syncthreads();

    const int row0    = blockIdx.x * rows_per_block;
    const int row_end = min(row0 + rows_per_block, N_NODES);

    for (int rb = row0; rb < row_end; rb += 32) {
        // stage 32 rows of x, transposed + swizzled.
        // thread (cg, rg) pass p: row r = p*8+rg, k = 4*cg+i.
        #pragma unroll
        for (int p = 0; p < 4; ++p) {
            const int r    = p * 8 + rg;
            const int grow = rb + r;
            float4 f = {0.f, 0.f, 0.f, 0.f};
            if (grow < N_NODES)
                f = reinterpret_cast<const float4*>(&x[(size_t)grow * CH])[cg];
            const int sw   = (((r >> 2) ^ (cg & 7)) << 2) + (r & 3);
            const int base = (4 * cg) << 5;            // word (4cg+i)*32
            xs[base      + sw] = f.x;
            xs[base + 32 + sw] = f.y;
            xs[base + 64 + sw] = f.z;
            xs[base + 96 + sw] = f.w;
        }
        __syncthreads();

        float acc[4][4];
        #pragma unroll
        for (int i = 0; i < 4; ++i)
            #pragma unroll
            for (int j = 0; j < 4; ++j) acc[i][j] = 0.f;

        #pragma unroll 8
        for (int k = 0; k < 128; ++k) {
            const float4 wv = *reinterpret_cast<const float4*>(
                &wt[(k << 7) + ((cg ^ (k & 31)) << 2)]);
            const float4 xv = *reinterpret_cast<const float4*>(
                &xs[(k << 5) + ((rg ^ ((k >> 2) & 7)) << 2)]);
            acc[0][0] += xv.x * wv.x; acc[0][1] += xv.x * wv.y;
            acc[0][2] += xv.x * wv.z; acc[0][3] += xv.x * wv.w;
            acc[1][0] += xv.y * wv.x; acc[1][1] += xv.y * wv.y;
            acc[1][2] += xv.y * wv.z; acc[1][3] += xv.y * wv.w;
            acc[2][0] += xv.z * wv.x; acc[2][1] += xv.z * wv.y;
            acc[2][2] += xv.z * wv.z; acc[2][3] += xv.z * wv.w;
            acc[3][0] += xv.w * wv.x; acc[3][1] += xv.w * wv.y;
            acc[3][2] += xv.w * wv.z; acc[3][3] += xv.w * wv.w;
        }

        #pragma unroll
        for (int i = 0; i < 4; ++i) {
            const int grow = rb + 4 * rg + i;
            if (grow < N_NODES) {
                float2 lo = make_float2(acc[i][0] + bias.x, acc[i][1] + bias.y);
                float2 hi = make_float2(acc[i][2] + bias.z, acc[i][3] + bias.w);
                __half2 h01 = __float22half2_rn(lo);
                __half2 h23 = __float22half2_rn(hi);
                uint2 pk;
                pk.x = *reinterpret_cast<unsigned int*>(&h01);
                pk.y = *reinterpret_cast<unsigned int*>(&h23);
                *reinterpret_cast<uint2*>(&xt[(size_t)grow * CH + 4 * cg]) = pk;
            }
        }
        __syncthreads();
    }
}

// ---------------------------------------------------------------------------
// CSR build (unchanged from round 3)
// ---------------------------------------------------------------------------
__global__ __launch_bounds__(256) void hist_deg(const int* __restrict__ ei,
                                                int* __restrict__ deg) {
    const int e = blockIdx.x * 256 + threadIdx.x;
    if (e < N_EDGES) atomicAdd(&deg[ei[e]], 1);
}

__global__ __launch_bounds__(1024) void scan_deg(const int* __restrict__ deg,
                                                 int* __restrict__ offs) {
    __shared__ int sums[1024];
    const int t = threadIdx.x;
    const int CHUNK = (N_NODES + 1023) / 1024;   // 49
    const int lo = t * CHUNK;
    const int hi = min(lo + CHUNK, N_NODES);
    int s = 0;
    for (int i = lo; i < hi; ++i) s += deg[i];
    sums[t] = s;
    __syncthreads();
    for (int d = 1; d < 1024; d <<= 1) {         // Hillis-Steele inclusive
        int v = (t >= d) ? sums[t - d] : 0;
        __syncthreads();
        sums[t] += v;
        __syncthreads();
    }
    int run = (t == 0) ? 0 : sums[t - 1];        // exclusive prefix of chunk
    for (int i = lo; i < hi; ++i) { offs[i] = run; run += deg[i]; }
    if (t == 1023) offs[N_NODES] = sums[1023];
}

// After this kernel offs[r] = segment END of r (= original offs[r+1]).
__global__ __launch_bounds__(256) void fill_csr(const int* __restrict__ ei,
                                                int* __restrict__ offs,
                                                int* __restrict__ csr) {
    const int e = blockIdx.x * 256 + threadIdx.x;
    if (e < N_EDGES) {
        const int r = ei[e];
        const int p = atomicAdd(&offs[r], 1);
        csr[p] = ei[N_EDGES + e];
    }
}

// ---------------------------------------------------------------------------
// Gather: one wave per node, 64 lanes x 2 fp16 channels. tanh fused.
// Segment of node n is [ n==0 ? 0 : offs[n-1], offs[n] ) after fill_csr.
// ---------------------------------------------------------------------------
__global__ __launch_bounds__(256) void gather_tanh(const int* __restrict__ offs,
                                                   const int* __restrict__ csr,
                                                   const __half* __restrict__ xt,
                                                   float* __restrict__ out) {
    const int wave = (blockIdx.x * 256 + threadIdx.x) >> 6;
    if (wave >= N_NODES) return;
    const int lane = threadIdx.x & 63;
    const int start = (wave == 0) ? 0 : offs[wave - 1];
    const int end   = offs[wave];

    float ax = 0.f, ay = 0.f;
    int i = start;
    for (; i + 4 <= end; i += 4) {
        const int c0 = csr[i], c1 = csr[i + 1], c2 = csr[i + 2], c3 = csr[i + 3];
        const float2 v0 = __half22float2(*reinterpret_cast<const __half2*>(
            &xt[(size_t)c0 * CH + lane * 2]));
        const float2 v1 = __half22float2(*reinterpret_cast<const __half2*>(
            &xt[(size_t)c1 * CH + lane * 2]));
        const float2 v2 = __half22float2(*reinterpret_cast<const __half2*>(
            &xt[(size_t)c2 * CH + lane * 2]));
        const float2 v3 = __half22float2(*reinterpret_cast<const __half2*>(
            &xt[(size_t)c3 * CH + lane * 2]));
        ax += v0.x + v1.x + v2.x + v3.x;
        ay += v0.y + v1.y + v2.y + v3.y;
    }
    for (; i < end; ++i) {
        const int c = csr[i];
        const float2 v = __half22float2(*reinterpret_cast<const __half2*>(
            &xt[(size_t)c * CH + lane * 2]));
        ax += v.x; ay += v.y;
    }
    float2 o;
    o.x = tanhf(ax);
    o.y = tanhf(ay);
    *reinterpret_cast<float2*>(&out[(size_t)wave * CH + lane * 2]) = o;
}

// ---------------------------------------------------------------------------
// Fallback path (ws too small): atomic scatter + tanh
// ---------------------------------------------------------------------------
__global__ __launch_bounds__(256) void scatter_add(const int* __restrict__ ei,
                                                   const __half* __restrict__ xt,
                                                   float* __restrict__ out) {
    const int gid = blockIdx.x * 256 + threadIdx.x;
    const int e = gid >> 5;
    if (e >= N_EDGES) return;
    const int lane = gid & 31;
    const int row = ei[e];
    const int col = ei[N_EDGES + e];
    const float2 va = __half22float2(*reinterpret_cast<const __half2*>(
        &xt[(size_t)col * CH + lane * 4]));
    const float2 vb = __half22float2(*reinterpret_cast<const __half2*>(
        &xt[(size_t)col * CH + lane * 4 + 2]));
    float* dst = &out[(size_t)row * CH + lane * 4];
    atomicAdd(dst + 0, va.x);
    atomicAdd(dst + 1, va.y);
    atomicAdd(dst + 2, vb.x);
    atomicAdd(dst + 3, vb.y);
}

__global__ __launch_bounds__(256) void tanh_inplace(float* __restrict__ out) {
    const int i = blockIdx.x * 256 + threadIdx.x;
    if (i < N_NODES * CH / 4) {
        float4* p = reinterpret_cast<float4*>(out);
        float4 v = p[i];
        v.x = tanhf(v.x); v.y = tanhf(v.y);
        v.z = tanhf(v.z); v.w = tanhf(v.w);
        p[i] = v;
    }
}

extern "C" void kernel_launch(void* const* d_in, const int* in_sizes, int n_in,
                              void* d_out, int out_size, void* d_ws, size_t ws_size,
                              hipStream_t stream) {
    const float* x  = (const float*)d_in[0];
    const int*   ei = (const int*)d_in[1];
    const float* W  = (const float*)d_in[2];
    const float* b  = (const float*)d_in[3];
    float* out = (float*)d_out;

    // ws layout (xt now fp16)
    const size_t XT_B   = (size_t)N_NODES * CH * sizeof(__half);  // 12,800,000
    const size_t DEG_O  = XT_B;                                   // deg: 50000 ints
    const size_t OFFS_O = DEG_O + (size_t)N_NODES * 4;            // offs: 50001 ints
    size_t CSR_O = OFFS_O + (size_t)(N_NODES + 1) * 4;
    CSR_O = (CSR_O + 255) & ~(size_t)255;
    const size_t NEED = CSR_O + (size_t)N_EDGES * 4;

    __half* xt = (__half*)d_ws;

    const int rpb = 96;                                // rows per block (mult of 32)
    const int gblocks = (N_NODES + rpb - 1) / rpb;     // 521
    gemm_xt_f16<<<gblocks, 256, 0, stream>>>(x, W, b, xt, rpb);

    if (ws_size >= NEED) {
        int* deg  = (int*)((char*)d_ws + DEG_O);
        int* offs = (int*)((char*)d_ws + OFFS_O);
        int* csr  = (int*)((char*)d_ws + CSR_O);

        hipMemsetAsync(deg, 0, (size_t)N_NODES * 4, stream);
        const int eblocks = (N_EDGES + 255) / 256;
        hist_deg<<<eblocks, 256, 0, stream>>>(ei, deg);
        scan_deg<<<1, 1024, 0, stream>>>(deg, offs);
        fill_csr<<<eblocks, 256, 0, stream>>>(ei, offs, csr);

        const int nblocks = (N_NODES * 64 + 255) / 256;  // one wave per node
        gather_tanh<<<nblocks, 256, 0, stream>>>(offs, csr, xt, out);
    } else {
        hipMemsetAsync(d_out, 0, (size_t)N_NODES * CH * sizeof(float), stream);
        const int sblocks = (N_EDGES * 32 + 255) / 256;
        scatter_add<<<sblocks, 256, 0, stream>>>(ei, xt, out);
        const int tblocks = (N_NODES * CH / 4 + 255) / 256;
        tanh_inplace<<<tblocks, 256, 0, stream>>>(out);
    }
}

// Round 7
// 250.831 us; speedup vs baseline: 5.9558x; 1.2889x over previous
//
#include <hip/hip_runtime.h>
#include <hip/hip_bf16.h>
#include <hip/hip_fp16.h>
#include <math.h>

#define N_NODES 50000
#define N_EDGES 800000
#define CH 128
#define SCAN_BLOCKS ((N_NODES + 255) / 256)   // 196

// ---------------------------------------------------------------------------
// Kernel 1: xt (fp16) = x @ W^T + b
// 256 threads = 32 col-groups (4 cols) x 8 row-groups (4 rows) -> 32r x 128c
// per tile. Both W^T and the x-tile live in LDS transposed ([k][...]) with
// XOR swizzle; per k each thread does 2 b128 reads feeding 16 fp32 FMAs.
// ---------------------------------------------------------------------------
__global__ __launch_bounds__(256) void gemm_xt_f16(const float* __restrict__ x,
                                                   const float* __restrict__ W,
                                                   const float* __restrict__ bias_p,
                                                   __half* __restrict__ xt,
                                                   int rows_per_block) {
    __shared__ float wt[128 * 128];   // 64 KB
    __shared__ float xs[128 * 32];    // 16 KB (32-row x-tile, transposed)

    const int tid = threadIdx.x;
    const int cg  = tid & 31;   // col group (4 cols)
    const int rg  = tid >> 5;   // row group (4 rows), 0..7

    for (int i = tid; i < 128 * 128; i += 256) {
        int c = i >> 7, k = i & 127;
        wt[(k << 7) + ((((c >> 2) ^ (k & 31))) << 2) + (c & 3)] = W[i];
    }
    const float4 bias = reinterpret_cast<const float4*>(bias_p)[cg];
    __syncthreads();

    const int row0    = blockIdx.x * rows_per_block;
    const int row_end = min(row0 + rows_per_block, N_NODES);

    for (int rb = row0; rb < row_end; rb += 32) {
        #pragma unroll
        for (int p = 0; p < 4; ++p) {
            const int r    = p * 8 + rg;
            const int grow = rb + r;
            float4 f = {0.f, 0.f, 0.f, 0.f};
            if (grow < N_NODES)
                f = reinterpret_cast<const float4*>(&x[(size_t)grow * CH])[cg];
            const int sw   = (((r >> 2) ^ (cg & 7)) << 2) + (r & 3);
            const int base = (4 * cg) << 5;            // word (4cg+i)*32
            xs[base      + sw] = f.x;
            xs[base + 32 + sw] = f.y;
            xs[base + 64 + sw] = f.z;
            xs[base + 96 + sw] = f.w;
        }
        __syncthreads();

        float acc[4][4];
        #pragma unroll
        for (int i = 0; i < 4; ++i)
            #pragma unroll
            for (int j = 0; j < 4; ++j) acc[i][j] = 0.f;

        #pragma unroll 8
        for (int k = 0; k < 128; ++k) {
            const float4 wv = *reinterpret_cast<const float4*>(
                &wt[(k << 7) + ((cg ^ (k & 31)) << 2)]);
            const float4 xv = *reinterpret_cast<const float4*>(
                &xs[(k << 5) + ((rg ^ ((k >> 2) & 7)) << 2)]);
            acc[0][0] += xv.x * wv.x; acc[0][1] += xv.x * wv.y;
            acc[0][2] += xv.x * wv.z; acc[0][3] += xv.x * wv.w;
            acc[1][0] += xv.y * wv.x; acc[1][1] += xv.y * wv.y;
            acc[1][2] += xv.y * wv.z; acc[1][3] += xv.y * wv.w;
            acc[2][0] += xv.z * wv.x; acc[2][1] += xv.z * wv.y;
            acc[2][2] += xv.z * wv.z; acc[2][3] += xv.z * wv.w;
            acc[3][0] += xv.w * wv.x; acc[3][1] += xv.w * wv.y;
            acc[3][2] += xv.w * wv.z; acc[3][3] += xv.w * wv.w;
        }

        #pragma unroll
        for (int i = 0; i < 4; ++i) {
            const int grow = rb + 4 * rg + i;
            if (grow < N_NODES) {
                float2 lo = make_float2(acc[i][0] + bias.x, acc[i][1] + bias.y);
                float2 hi = make_float2(acc[i][2] + bias.z, acc[i][3] + bias.w);
                __half2 h01 = __float22half2_rn(lo);
                __half2 h23 = __float22half2_rn(hi);
                uint2 pk;
                pk.x = *reinterpret_cast<unsigned int*>(&h01);
                pk.y = *reinterpret_cast<unsigned int*>(&h23);
                *reinterpret_cast<uint2*>(&xt[(size_t)grow * CH + 4 * cg]) = pk;
            }
        }
        __syncthreads();
    }
}

// ---------------------------------------------------------------------------
// CSR build — parallel scan version
// ---------------------------------------------------------------------------
__global__ __launch_bounds__(256) void hist_deg(const int* __restrict__ ei,
                                                int* __restrict__ deg) {
    const int e = blockIdx.x * 256 + threadIdx.x;
    if (e < N_EDGES) atomicAdd(&deg[ei[e]], 1);
}

// Block-local exclusive prefix of deg -> offs; block totals -> psum.
__global__ __launch_bounds__(256) void scan_local(const int* __restrict__ deg,
                                                  int* __restrict__ offs,
                                                  int* __restrict__ psum) {
    __shared__ int s[256];
    const int t = threadIdx.x;
    const int i = blockIdx.x * 256 + t;
    const int d = (i < N_NODES) ? deg[i] : 0;
    s[t] = d;
    __syncthreads();
    #pragma unroll
    for (int off = 1; off < 256; off <<= 1) {   // Hillis-Steele inclusive
        int v = (t >= off) ? s[t - off] : 0;
        __syncthreads();
        s[t] += v;
        __syncthreads();
    }
    if (i < N_NODES) offs[i] = s[t] - d;        // exclusive, block-local
    if (t == 255) psum[blockIdx.x] = s[255];
}

// Exclusive scan of the SCAN_BLOCKS block totals -> pbase.
__global__ __launch_bounds__(256) void scan_psum(const int* __restrict__ psum,
                                                 int* __restrict__ pbase) {
    __shared__ int s[256];
    const int t = threadIdx.x;
    const int v = (t < SCAN_BLOCKS) ? psum[t] : 0;
    s[t] = v;
    __syncthreads();
    #pragma unroll
    for (int off = 1; off < 256; off <<= 1) {
        int u = (t >= off) ? s[t - off] : 0;
        __syncthreads();
        s[t] += u;
        __syncthreads();
    }
    if (t < SCAN_BLOCKS) pbase[t] = s[t] - v;
}

// After this kernel offs[r] = LOCAL segment end; global end = offs[r]+pbase[r>>8].
__global__ __launch_bounds__(256) void fill_csr(const int* __restrict__ ei,
                                                int* __restrict__ offs,
                                                const int* __restrict__ pbase,
                                                int* __restrict__ csr) {
    const int e = blockIdx.x * 256 + threadIdx.x;
    if (e < N_EDGES) {
        const int r = ei[e];
        const int p = atomicAdd(&offs[r], 1) + pbase[r >> 8];
        csr[p] = ei[N_EDGES + e];
    }
}

// ---------------------------------------------------------------------------
// Gather: one wave per node, 64 lanes x 2 fp16 channels. tanh fused.
// Global segment of node n: [ offs[n-1]+pbase[(n-1)>>8]  (0 if n==0),
//                             offs[n]+pbase[n>>8] )     after fill_csr.
// ---------------------------------------------------------------------------
__global__ __launch_bounds__(256) void gather_tanh(const int* __restrict__ offs,
                                                   const int* __restrict__ pbase,
                                                   const int* __restrict__ csr,
                                                   const __half* __restrict__ xt,
                                                   float* __restrict__ out) {
    const int wave = (blockIdx.x * 256 + threadIdx.x) >> 6;
    if (wave >= N_NODES) return;
    const int lane = threadIdx.x & 63;
    const int start = (wave == 0) ? 0 : offs[wave - 1] + pbase[(wave - 1) >> 8];
    const int end   = offs[wave] + pbase[wave >> 8];

    float ax = 0.f, ay = 0.f;
    int i = start;
    for (; i + 4 <= end; i += 4) {
        const int c0 = csr[i], c1 = csr[i + 1], c2 = csr[i + 2], c3 = csr[i + 3];
        const float2 v0 = __half22float2(*reinterpret_cast<const __half2*>(
            &xt[(size_t)c0 * CH + lane * 2]));
        const float2 v1 = __half22float2(*reinterpret_cast<const __half2*>(
            &xt[(size_t)c1 * CH + lane * 2]));
        const float2 v2 = __half22float2(*reinterpret_cast<const __half2*>(
            &xt[(size_t)c2 * CH + lane * 2]));
        const float2 v3 = __half22float2(*reinterpret_cast<const __half2*>(
            &xt[(size_t)c3 * CH + lane * 2]));
        ax += v0.x + v1.x + v2.x + v3.x;
        ay += v0.y + v1.y + v2.y + v3.y;
    }
    for (; i < end; ++i) {
        const int c = csr[i];
        const float2 v = __half22float2(*reinterpret_cast<const __half2*>(
            &xt[(size_t)c * CH + lane * 2]));
        ax += v.x; ay += v.y;
    }
    float2 o;
    o.x = tanhf(ax);
    o.y = tanhf(ay);
    *reinterpret_cast<float2*>(&out[(size_t)wave * CH + lane * 2]) = o;
}

// ---------------------------------------------------------------------------
// Fallback path (ws too small): atomic scatter + tanh
// ---------------------------------------------------------------------------
__global__ __launch_bounds__(256) void scatter_add(const int* __restrict__ ei,
                                                   const __half* __restrict__ xt,
                                                   float* __restrict__ out) {
    const int gid = blockIdx.x * 256 + threadIdx.x;
    const int e = gid >> 5;
    if (e >= N_EDGES) return;
    const int lane = gid & 31;
    const int row = ei[e];
    const int col = ei[N_EDGES + e];
    const float2 va = __half22float2(*reinterpret_cast<const __half2*>(
        &xt[(size_t)col * CH + lane * 4]));
    const float2 vb = __half22float2(*reinterpret_cast<const __half2*>(
        &xt[(size_t)col * CH + lane * 4 + 2]));
    float* dst = &out[(size_t)row * CH + lane * 4];
    atomicAdd(dst + 0, va.x);
    atomicAdd(dst + 1, va.y);
    atomicAdd(dst + 2, vb.x);
    atomicAdd(dst + 3, vb.y);
}

__global__ __launch_bounds__(256) void tanh_inplace(float* __restrict__ out) {
    const int i = blockIdx.x * 256 + threadIdx.x;
    if (i < N_NODES * CH / 4) {
        float4* p = reinterpret_cast<float4*>(out);
        float4 v = p[i];
        v.x = tanhf(v.x); v.y = tanhf(v.y);
        v.z = tanhf(v.z); v.w = tanhf(v.w);
        p[i] = v;
    }
}

extern "C" void kernel_launch(void* const* d_in, const int* in_sizes, int n_in,
                              void* d_out, int out_size, void* d_ws, size_t ws_size,
                              hipStream_t stream) {
    const float* x  = (const float*)d_in[0];
    const int*   ei = (const int*)d_in[1];
    const float* W  = (const float*)d_in[2];
    const float* b  = (const float*)d_in[3];
    float* out = (float*)d_out;

    // ws layout (xt fp16)
    const size_t XT_B    = (size_t)N_NODES * CH * sizeof(__half); // 12,800,000
    const size_t DEG_O   = XT_B;
    const size_t OFFS_O  = DEG_O  + (size_t)N_NODES * 4;
    const size_t PSUM_O  = OFFS_O + (size_t)(N_NODES + 1) * 4;
    const size_t PBASE_O = PSUM_O + (size_t)SCAN_BLOCKS * 4;
    size_t CSR_O = PBASE_O + (size_t)SCAN_BLOCKS * 4;
    CSR_O = (CSR_O + 255) & ~(size_t)255;
    const size_t NEED = CSR_O + (size_t)N_EDGES * 4;

    __half* xt = (__half*)d_ws;

    const int rpb = 96;                                // rows per block (mult of 32)
    const int gblocks = (N_NODES + rpb - 1) / rpb;     // 521
    gemm_xt_f16<<<gblocks, 256, 0, stream>>>(x, W, b, xt, rpb);

    if (ws_size >= NEED) {
        int* deg   = (int*)((char*)d_ws + DEG_O);
        int* offs  = (int*)((char*)d_ws + OFFS_O);
        int* psum  = (int*)((char*)d_ws + PSUM_O);
        int* pbase = (int*)((char*)d_ws + PBASE_O);
        int* csr   = (int*)((char*)d_ws + CSR_O);

        hipMemsetAsync(deg, 0, (size_t)N_NODES * 4, stream);
        const int eblocks = (N_EDGES + 255) / 256;
        hist_deg<<<eblocks, 256, 0, stream>>>(ei, deg);
        scan_local<<<SCAN_BLOCKS, 256, 0, stream>>>(deg, offs, psum);
        scan_psum<<<1, 256, 0, stream>>>(psum, pbase);
        fill_csr<<<eblocks, 256, 0, stream>>>(ei, offs, pbase, csr);

        const int nblocks = (N_NODES * 64 + 255) / 256;  // one wave per node
        gather_tanh<<<nblocks, 256, 0, stream>>>(offs, pbase, csr, xt, out);
    } else {
        hipMemsetAsync(d_out, 0, (size_t)N_NODES * CH * sizeof(float), stream);
        const int sblocks = (N_EDGES * 32 + 255) / 256;
        scatter_add<<<sblocks, 256, 0, stream>>>(ei, xt, out);
        const int tblocks = (N_NODES * CH / 4 + 255) / 256;
        tanh_inplace<<<tblocks, 256, 0, stream>>>(out);
    }
}